// Round 1
// baseline (207.295 us; speedup 1.0000x reference)
//
#include <hip/hip_runtime.h>
#include <math.h>

#define NN 8192
#define CC 4096
#define SLOTS 64
#define CB 512               // threads per class-block (8 waves); each thread owns 2 float4 slots
#define NF4 (CC / 4)         // 1024 float4 per feature row

// out = sum_c cnt_c * value_c * NUM_POS / N^2 ; NUM_POS=4, N=8192
#define SCALE (4.0f / (8192.0f * 8192.0f))

__global__ void init_kernel(int* __restrict__ counts) {
    int i = blockIdx.x * blockDim.x + threadIdx.x;
    if (i < CC) counts[i] = 0;
}

__global__ void build_index(const int* __restrict__ label,
                            int* __restrict__ counts,
                            int* __restrict__ lists) {
    int i = blockIdx.x * blockDim.x + threadIdx.x;
    if (i < NN) {
        int lab = label[i];
        int pos = atomicAdd(&counts[lab], 1);
        if (pos < SLOTS) lists[lab * SLOTS + pos] = i;
    }
}

// Tiered gather over both of this thread's float4 slots. T loads per slot issued
// back-to-back (single vmcnt drain); tail rows duplicate row 0 with weight 0
// (dup loads hit L1/L2 — same addresses as k=0 — ~free).
template <int T>
__device__ inline void gather2(const float4* __restrict__ feat4,
                               const int* __restrict__ rl, int m,
                               int s0, int s1, float4& a0, float4& a1) {
    int r0 = rl[0];
    float4 v0[T], v1[T];
    #pragma unroll
    for (int k = 0; k < T; ++k) {
        int r = (k < m) ? rl[k] : r0;
        size_t rb = (size_t)r * NF4;
        v0[k] = feat4[rb + s0];
        v1[k] = feat4[rb + s1];
    }
    #pragma unroll
    for (int k = 0; k < T; ++k) {
        float w = (k < m) ? 1.f : 0.f;
        a0.x += w * v0[k].x; a0.y += w * v0[k].y; a0.z += w * v0[k].z; a0.w += w * v0[k].w;
        a1.x += w * v1[k].x; a1.y += w * v1[k].y; a1.z += w * v1[k].z; a1.w += w * v1[k].w;
    }
}

// One block per class. Thread t owns float4 slots {t, t+CB} = columns
// [4t..4t+3] and [2048+4t..2048+4t+3]. Each member row is read as one
// contiguous 16 KB burst by the block (DRAM page locality), the full
// logsumexp is computed in-block, and a single contrib[c] is written.
__global__ __launch_bounds__(CB) void center_kernel(const float4* __restrict__ feat4,
                                                    const int* __restrict__ counts,
                                                    const int* __restrict__ lists,
                                                    float* __restrict__ contrib) {
    int c = blockIdx.x;
    int t = threadIdx.x;
    int cnt = counts[c];               // uniform -> scalar load
    if (cnt == 0) {                    // block-uniform exit
        if (t == 0) contrib[c] = 0.f;
        return;
    }
    int m = cnt < SLOTS ? cnt : SLOTS;
    const int* rl = lists + c * SLOTS;

    float4 a0 = make_float4(0.f, 0.f, 0.f, 0.f);
    float4 a1 = make_float4(0.f, 0.f, 0.f, 0.f);
    if (m == 1)      gather2<1>(feat4, rl, m, t, t + CB, a0, a1);
    else if (m == 2) gather2<2>(feat4, rl, m, t, t + CB, a0, a1);
    else if (m <= 4) gather2<4>(feat4, rl, m, t, t + CB, a0, a1);
    else {
        gather2<8>(feat4, rl, m < 8 ? m : 8, t, t + CB, a0, a1);
        for (int k = 8; k < m; ++k) {   // essentially never taken (Poisson(2))
            size_t rb = (size_t)rl[k] * NF4;
            float4 v0 = feat4[rb + t], v1 = feat4[rb + t + CB];
            a0.x += v0.x; a0.y += v0.y; a0.z += v0.z; a0.w += v0.w;
            a1.x += v1.x; a1.y += v1.y; a1.z += v1.z; a1.w += v1.w;
        }
    }

    float inv = 1.0f / (float)cnt;
    float e0[4] = {a0.x * inv, a0.y * inv, a0.z * inv, a0.w * inv};
    float e1[4] = {a1.x * inv, a1.y * inv, a1.z * inv, a1.w * inv};

    __shared__ float s_m[CB / 64], s_s[CB / 64], s_v;
    int lane = t & 63, w = t >> 6;

    // block max (wave shfl-reduce, then cross-wave via LDS)
    float M = fmaxf(fmaxf(fmaxf(e0[0], e0[1]), fmaxf(e0[2], e0[3])),
                    fmaxf(fmaxf(e1[0], e1[1]), fmaxf(e1[2], e1[3])));
    #pragma unroll
    for (int off = 1; off < 64; off <<= 1) M = fmaxf(M, __shfl_xor(M, off, 64));
    if (lane == 0) s_m[w] = M;

    // v at column c: float4 index sIdx = c>>2; owner thread t = sIdx & 511,
    // array chosen by sIdx >= 512, component c&3.
    int sIdx = c >> 2;
    if (t == (sIdx & (CB - 1))) s_v = (sIdx < CB) ? e0[c & 3] : e1[c & 3];
    __syncthreads();

    M = s_m[0];
    #pragma unroll
    for (int j = 1; j < CB / 64; ++j) M = fmaxf(M, s_m[j]);

    float S = __expf(e0[0] - M) + __expf(e0[1] - M) + __expf(e0[2] - M) + __expf(e0[3] - M)
            + __expf(e1[0] - M) + __expf(e1[1] - M) + __expf(e1[2] - M) + __expf(e1[3] - M);
    #pragma unroll
    for (int off = 1; off < 64; off <<= 1) S += __shfl_xor(S, off, 64);
    if (lane == 0) s_s[w] = S;
    __syncthreads();

    if (t == 0) {
        float Stot = 0.f;
        #pragma unroll
        for (int j = 0; j < CB / 64; ++j) Stot += s_s[j];
        contrib[c] = (float)cnt * (M + __logf(Stot) - s_v);
    }
}

// Single block: reduce 4096 per-class contributions, write out[0] directly
// (no atomic, no output zero-init needed).
__global__ __launch_bounds__(256) void finalize(const float* __restrict__ contrib,
                                                float* __restrict__ out) {
    float s = 0.f;
    for (int i = threadIdx.x; i < CC; i += 256) s += contrib[i];
    #pragma unroll
    for (int off = 1; off < 64; off <<= 1) s += __shfl_xor(s, off, 64);
    __shared__ float sr[4];
    int lane = threadIdx.x & 63, w = threadIdx.x >> 6;
    if (lane == 0) sr[w] = s;
    __syncthreads();
    if (threadIdx.x == 0) out[0] = (sr[0] + sr[1] + sr[2] + sr[3]) * SCALE;
}

extern "C" void kernel_launch(void* const* d_in, const int* in_sizes, int n_in,
                              void* d_out, int out_size, void* d_ws, size_t ws_size,
                              hipStream_t stream) {
    const float* feat = (const float*)d_in[0];
    const int* label = (const int*)d_in[1];
    float* out = (float*)d_out;

    int* counts = (int*)d_ws;                      // CC ints
    int* lists = counts + CC;                      // CC * SLOTS ints
    float* contrib = (float*)(lists + CC * SLOTS); // CC floats

    init_kernel<<<(CC + 255) / 256, 256, 0, stream>>>(counts);
    build_index<<<(NN + 255) / 256, 256, 0, stream>>>(label, counts, lists);
    center_kernel<<<CC, CB, 0, stream>>>((const float4*)feat, counts, lists, contrib);
    finalize<<<1, 256, 0, stream>>>(contrib, out);
}

// Round 2
// 201.113 us; speedup vs baseline: 1.0307x; 1.0307x over previous
//
#include <hip/hip_runtime.h>
#include <math.h>

#define NN 8192
#define CC 4096
#define SLOTS 64
#define BLK 256
#define NSPLIT 4     // 4 column splits of 1024 cols (4 KB) per class; one WAVE per (class,split)
#define NF4 (CC / 4) // 1024 float4 per feature row

// out = sum_c cnt_c * value_c * NUM_POS / N^2 ; NUM_POS=4, N=8192
#define SCALE (4.0f / (8192.0f * 8192.0f))

__global__ void init_kernel(int* __restrict__ counts, float* __restrict__ out) {
    int i = blockIdx.x * blockDim.x + threadIdx.x;
    if (i < CC) counts[i] = 0;
    if (i == 0) out[0] = 0.0f;
}

__global__ void build_index(const int* __restrict__ label,
                            int* __restrict__ counts,
                            int* __restrict__ lists) {
    int i = blockIdx.x * blockDim.x + threadIdx.x;
    if (i < NN) {
        int lab = label[i];
        int pos = atomicAdd(&counts[lab], 1);
        if (pos < SLOTS) lists[lab * SLOTS + pos] = i;
    }
}

// Tiered gather: T rows x 4 float4 slots, all loads issued back-to-back
// (single vmcnt drain). Tail rows duplicate row 0 with weight 0 (dup loads
// hit L1 -- same addresses as k=0 -- ~free).
template <int T>
__device__ inline void gather4(const float4* __restrict__ feat4,
                               const int* __restrict__ rl, int m,
                               int slot, float4 acc[4]) {
    int r0 = rl[0];
    float4 v[T][4];
    #pragma unroll
    for (int k = 0; k < T; ++k) {
        int r = (k < m) ? rl[k] : r0;
        size_t rb = (size_t)r * NF4 + slot;
        #pragma unroll
        for (int j = 0; j < 4; ++j) v[k][j] = feat4[rb + j * 64];
    }
    #pragma unroll
    for (int k = 0; k < T; ++k) {
        float w = (k < m) ? 1.f : 0.f;
        #pragma unroll
        for (int j = 0; j < 4; ++j) {
            acc[j].x += w * v[k][j].x; acc[j].y += w * v[k][j].y;
            acc[j].z += w * v[k][j].z; acc[j].w += w * v[k][j].w;
        }
    }
}

// One wave per (class c, split s). Lane l owns float4 slots s*256 + l + 64j
// (j=0..3), i.e. 4 coalesced 1 KB wave-loads per row; the block's 4 waves are
// the 4 splits of ONE class, so each row is fetched as one 16 KB burst.
// No LDS, no __syncthreads. Writes part[s*CC + c] = (M_s, S_s, vc_s).
__global__ __launch_bounds__(BLK) void part_kernel(const float4* __restrict__ feat4,
                                                   const int* __restrict__ counts,
                                                   const int* __restrict__ lists,
                                                   float4* __restrict__ part) {
    int lane = threadIdx.x & 63;
    int wv = __builtin_amdgcn_readfirstlane(threadIdx.x >> 6);  // force scalar
    int task = blockIdx.x * 4 + wv;
    int c = task >> 2;
    int s = task & 3;

    int cnt = counts[c];            // uniform -> scalar load
    if (cnt == 0) return;           // wave-uniform exit; finalize skips these
    int m = cnt < SLOTS ? cnt : SLOTS;

    const int* rl = lists + c * SLOTS;
    int slot = s * 256 + lane;

    float4 acc[4];
    #pragma unroll
    for (int j = 0; j < 4; ++j) acc[j] = make_float4(0.f, 0.f, 0.f, 0.f);

    if (m == 1)      gather4<1>(feat4, rl, m, slot, acc);
    else if (m == 2) gather4<2>(feat4, rl, m, slot, acc);
    else if (m <= 4) gather4<4>(feat4, rl, m, slot, acc);
    else {
        gather4<4>(feat4, rl, 4, slot, acc);
        for (int k = 4; k < m; ++k) {          // ~5% of classes (Poisson(2))
            size_t rb = (size_t)rl[k] * NF4 + slot;
            #pragma unroll
            for (int j = 0; j < 4; ++j) {
                float4 v = feat4[rb + j * 64];
                acc[j].x += v.x; acc[j].y += v.y; acc[j].z += v.z; acc[j].w += v.w;
            }
        }
    }

    float inv = 1.0f / (float)cnt;
    float4 mean[4];
    #pragma unroll
    for (int j = 0; j < 4; ++j) {
        mean[j].x = acc[j].x * inv; mean[j].y = acc[j].y * inv;
        mean[j].z = acc[j].z * inv; mean[j].w = acc[j].w * inv;
    }

    // wave max over this split's 4096/NSPLIT columns
    float M = -1e30f;
    #pragma unroll
    for (int j = 0; j < 4; ++j)
        M = fmaxf(M, fmaxf(fmaxf(mean[j].x, mean[j].y), fmaxf(mean[j].z, mean[j].w)));
    #pragma unroll
    for (int off = 1; off < 64; off <<= 1) M = fmaxf(M, __shfl_xor(M, off, 64));

    // wave sum of exp
    float S = 0.f;
    #pragma unroll
    for (int j = 0; j < 4; ++j)
        S += __expf(mean[j].x - M) + __expf(mean[j].y - M) +
             __expf(mean[j].z - M) + __expf(mean[j].w - M);
    #pragma unroll
    for (int off = 1; off < 64; off <<= 1) S += __shfl_xor(S, off, 64);

    // v at column c: split c>>10, within-split float4 idx = (c>>2)&255,
    // owner lane = idx&63, j = idx>>6, component c&3. Static-index select
    // (16 cndmasks) to avoid scratch (runtime-indexed reg array).
    int sIdx = (c >> 2) & 255;
    int jj = sIdx >> 6, comp = c & 3;
    float cand = 0.f;
    #pragma unroll
    for (int j = 0; j < 4; ++j) {
        cand = (jj == j && comp == 0) ? mean[j].x : cand;
        cand = (jj == j && comp == 1) ? mean[j].y : cand;
        cand = (jj == j && comp == 2) ? mean[j].z : cand;
        cand = (jj == j && comp == 3) ? mean[j].w : cand;
    }
    float vcown = __shfl(cand, sIdx & 63, 64);
    float vc = (s == (c >> 10)) ? vcown : 0.f;

    if (lane == 0) part[s * CC + c] = make_float4(M, S, vc, 0.f);
}

// Combine 4 splits per class (exact logsumexp merge), weight by cnt, reduce.
__global__ __launch_bounds__(BLK) void finalize(const float4* __restrict__ part,
                                                const int* __restrict__ counts,
                                                float* __restrict__ out) {
    int c = blockIdx.x * BLK + threadIdx.x;   // 16 blocks x 256 = 4096
    int cnt = counts[c];
    float contrib = 0.f;
    if (cnt > 0) {
        float4 p[NSPLIT];
        #pragma unroll
        for (int s = 0; s < NSPLIT; ++s) p[s] = part[s * CC + c];  // coalesced per s
        float M = p[0].x;
        #pragma unroll
        for (int s = 1; s < NSPLIT; ++s) M = fmaxf(M, p[s].x);
        float S = 0.f, vc = 0.f;
        #pragma unroll
        for (int s = 0; s < NSPLIT; ++s) {
            S += p[s].y * __expf(p[s].x - M);
            vc += p[s].z;   // non-owning splits contributed 0
        }
        contrib = (float)cnt * (M + __logf(S) - vc);
    }

    #pragma unroll
    for (int off = 1; off < 64; off <<= 1) contrib += __shfl_xor(contrib, off, 64);
    __shared__ float s_red[4];
    int lane = threadIdx.x & 63, w = threadIdx.x >> 6;
    if (lane == 0) s_red[w] = contrib;
    __syncthreads();
    if (threadIdx.x == 0)
        atomicAdd(out, (s_red[0] + s_red[1] + s_red[2] + s_red[3]) * SCALE);
}

extern "C" void kernel_launch(void* const* d_in, const int* in_sizes, int n_in,
                              void* d_out, int out_size, void* d_ws, size_t ws_size,
                              hipStream_t stream) {
    const float* feat = (const float*)d_in[0];
    const int* label = (const int*)d_in[1];
    float* out = (float*)d_out;

    int* counts = (int*)d_ws;                      // CC ints
    int* lists = counts + CC;                      // CC * SLOTS ints
    float4* part = (float4*)(lists + CC * SLOTS);  // NSPLIT * CC float4 (256 KB)

    init_kernel<<<(CC + BLK - 1) / BLK, BLK, 0, stream>>>(counts, out);
    build_index<<<(NN + BLK - 1) / BLK, BLK, 0, stream>>>(label, counts, lists);
    part_kernel<<<CC * NSPLIT / 4, BLK, 0, stream>>>((const float4*)feat, counts, lists, part);
    finalize<<<CC / BLK, BLK, 0, stream>>>(part, counts, out);
}